// Round 18
// baseline (168.963 us; speedup 1.0000x reference)
//
#include <hip/hip_runtime.h>
#include <hip/hip_bf16.h>
#include <stdint.h>

#define B_    4
#define QL_   512
#define KVL_  4096
#define QDIM  1024
#define KVDIM 768
#define NCH   1024
#define H_    8
#define DH    128
#define NROWS (B_ * H_ * QL_)   // 16384 partial rows
#define KVBLK 64
#define NS    4

typedef unsigned short ushort_t;
typedef __attribute__((ext_vector_type(8))) short bf16x8;
typedef __attribute__((ext_vector_type(4))) float f32x4;
typedef __attribute__((ext_vector_type(4))) unsigned short us4;

__device__ __forceinline__ ushort_t f2bf(float x){
  union { float f; unsigned u; } v; v.f = x;
  unsigned r = v.u + 0x7FFF + ((v.u >> 16) & 1);
  return (ushort_t)(r >> 16);
}

__device__ __forceinline__ float bf2f(unsigned hs){
  union { unsigned u; float f; } v; v.u = hs << 16; return v.f;
}

__device__ __forceinline__ void gload16(void* l, const void* g){
  __builtin_amdgcn_global_load_lds(
    (const __attribute__((address_space(1))) unsigned int*)g,
    (__attribute__((address_space(3))) unsigned int*)l, 16, 0, 0);
}

// ---------------- LayerNorm + bf16 cast: wave-per-row, no LDS, no barrier ----------------
template<int D>
__global__ __launch_bounds__(256)
void ln_kernel(const float* __restrict__ x, const float* __restrict__ gamma,
               const float* __restrict__ beta, ushort_t* __restrict__ out){
  constexpr int NPT = D / 256;           // f32x4 per lane
  int w = threadIdx.x >> 6, lane = threadIdx.x & 63;
  int row = blockIdx.x * 4 + w;
  const f32x4* xr = (const f32x4*)(x + (size_t)row * D);
  f32x4 v[NPT];
  float s = 0.f, s2 = 0.f;
  #pragma unroll
  for (int k = 0; k < NPT; ++k){
    v[k] = xr[k * 64 + lane];
    #pragma unroll
    for (int e = 0; e < 4; ++e){ s += v[k][e]; s2 += v[k][e] * v[k][e]; }
  }
  #pragma unroll
  for (int m = 32; m; m >>= 1){ s += __shfl_xor(s, m); s2 += __shfl_xor(s2, m); }
  float mu  = s / D;
  float var = s2 / D - mu * mu;
  float rs  = rsqrtf(var + 1e-3f);
  us4* orow = (us4*)(out + (size_t)row * D);
  #pragma unroll
  for (int k = 0; k < NPT; ++k){
    f32x4 gm = ((const f32x4*)gamma)[k * 64 + lane];
    f32x4 bt = ((const f32x4*)beta)[k * 64 + lane];
    us4 o;
    #pragma unroll
    for (int e = 0; e < 4; ++e) o[e] = f2bf((v[k][e] - mu) * rs * gm[e] + bt[e]);
    orow[k * 64 + lane] = o;
  }
}

// ---------------- Fused weight transpose + bf16 cast (z selects matrix) ----------------
__global__ void wtrans_kernel(const float* __restrict__ Wq, ushort_t* __restrict__ Wqt,
                              const float* __restrict__ Wk, ushort_t* __restrict__ Wkt,
                              const float* __restrict__ Wv, ushort_t* __restrict__ Wvt){
  __shared__ float t[32][33];
  int z = blockIdx.z;
  const float* W = (z == 0) ? Wq : (z == 1) ? Wk : Wv;
  ushort_t* Wt   = (z == 0) ? Wqt : (z == 1) ? Wkt : Wvt;
  int K = (z == 0) ? 1024 : 768;
  int n0 = blockIdx.x * 32, k0 = blockIdx.y * 32;
  if (k0 >= K) return;
  int tx = threadIdx.x & 31, ty = threadIdx.x >> 5;   // 32 x 8
  #pragma unroll
  for (int i = 0; i < 32; i += 8) t[ty + i][tx] = W[(size_t)(k0 + ty + i) * NCH + n0 + tx];
  __syncthreads();
  #pragma unroll
  for (int i = 0; i < 32; i += 8)
    Wt[(size_t)(n0 + ty + i) * K + k0 + tx] = f2bf(t[tx][ty + i]);
}

// ---------------- small GEMM (Q): 128x128 tile, 3-buffer counted-vmcnt ----------------
__global__ __launch_bounds__(256)
void gemm_kernel(const ushort_t* __restrict__ A, const ushort_t* __restrict__ Bw,
                 const float* __restrict__ bias, ushort_t* __restrict__ out,
                 int M, int K, float oscale){
  __shared__ __align__(16) ushort_t lds[3][2][4][128][8];   // 48 KB, buf = ks%3
  int tid = threadIdx.x;
  int w = tid >> 6, lane = tid & 63;
  int m0 = blockIdx.x * 128, n0 = blockIdx.y * 128;
  int wr = w >> 1, wc = w & 1;
  int g = lane >> 4, j = lane & 15;
  f32x4 acc[4][4] = {};
  const int ksteps = K / 32;
  const ushort_t* Aw  = A  + (size_t)(m0 + lane) * K + w * 8;
  const ushort_t* Bww = Bw + (size_t)(n0 + lane) * K + w * 8;

  auto stage = [&](int buf, int ks){      // 4 loads/wave
    #pragma unroll
    for (int i = 0; i < 2; ++i){
      gload16(&lds[buf][0][w][i*64][0], Aw  + (size_t)i*64*K + ks*32);
      gload16(&lds[buf][1][w][i*64][0], Bww + (size_t)i*64*K + ks*32);
    }
  };

  stage(0, 0);
  stage(1, 1);
  asm volatile("s_waitcnt vmcnt(4)" ::: "memory");
  __builtin_amdgcn_s_barrier();
  __builtin_amdgcn_sched_barrier(0);

  int cur = 0;
  for (int ks = 0; ks < ksteps; ++ks){
    int nxt = cur + 2; if (nxt >= 3) nxt -= 3;
    bool pf = (ks + 2 < ksteps);
    if (pf) stage(nxt, ks + 2);
    bf16x8 af[4], bfr[4];
    #pragma unroll
    for (int mi = 0; mi < 4; ++mi) af[mi]  = *(const bf16x8*)&lds[cur][0][g][wr*64 + mi*16 + j][0];
    #pragma unroll
    for (int ni = 0; ni < 4; ++ni) bfr[ni] = *(const bf16x8*)&lds[cur][1][g][wc*64 + ni*16 + j][0];
    __builtin_amdgcn_s_setprio(1);
    #pragma unroll
    for (int mi = 0; mi < 4; ++mi)
      #pragma unroll
      for (int ni = 0; ni < 4; ++ni)
        acc[mi][ni] = __builtin_amdgcn_mfma_f32_16x16x32_bf16(af[mi], bfr[ni], acc[mi][ni], 0, 0, 0);
    __builtin_amdgcn_s_setprio(0);
    if (pf) asm volatile("s_waitcnt vmcnt(4)" ::: "memory");
    else    asm volatile("s_waitcnt vmcnt(0)" ::: "memory");
    __builtin_amdgcn_s_barrier();
    __builtin_amdgcn_sched_barrier(0);
    cur += 1; if (cur >= 3) cur -= 3;
  }

  #pragma unroll
  for (int mi = 0; mi < 4; ++mi){
    int row0 = m0 + wr*64 + mi*16 + g*4;
    #pragma unroll
    for (int ni = 0; ni < 4; ++ni){
      int col = n0 + wc*64 + ni*16 + j;
      float bs = bias[col];
      #pragma unroll
      for (int r = 0; r < 4; ++r)
        out[(size_t)(row0 + r) * NCH + col] = f2bf((acc[mi][ni][r] + bs) * oscale);
    }
  }
}

// ---------------- big GEMM (K/V): 256x128 tile, A 3-buf + B 3-buf = 72 KB -> 2 blocks/CU ----------------
// 8 waves (2M x 4N): per-wave output 128x32, acc[8][2]. 3 loads/thread/K-step -> vmcnt(3).
template<bool TRANSV>
__global__ __launch_bounds__(512, 2)
void gemm256_kernel(const ushort_t* __restrict__ A, const ushort_t* __restrict__ Bw,
                    const float* __restrict__ bias, ushort_t* __restrict__ out,
                    int M, int K, float oscale){
  __shared__ __align__(16) ushort_t abuf[3][256][32];   // 48 KB
  __shared__ __align__(16) ushort_t bbuf[3][128][32];   // 24 KB
  int tid = threadIdx.x;
  int w = tid >> 6, lane = tid & 63;
  int m0 = blockIdx.x * 256, n0 = blockIdx.y * 128;
  int wr = w >> 2, wc = w & 3;
  int g = lane >> 4, j = lane & 15;
  f32x4 acc[8][2] = {};
  const int ksteps = K / 32;
  int srow = tid >> 2;
  int cg = (tid & 3) ^ ((tid >> 3) & 3);                 // inverse-swizzled source col-group
  const ushort_t* Asrc = A  + (size_t)(m0 + srow) * K + cg * 8;
  const ushort_t* Bsrc = Bw + (size_t)(n0 + srow) * K + cg * 8;   // srow 0..127 used

  auto stage = [&](int buf, int ks){      // 3 gload16/thread (2 A + 1 B), linear LDS dest
    char* la = (char*)&abuf[buf][0][0] + tid * 16;
    char* lb = (char*)&bbuf[buf][0][0] + tid * 16;
    #pragma unroll
    for (int i = 0; i < 2; ++i)
      gload16(la + i*8192, Asrc + (size_t)(i*128)*K + ks*32);
    gload16(lb, Bsrc + ks*32);
  };

  stage(0, 0);
  stage(1, 1);
  asm volatile("s_waitcnt vmcnt(3)" ::: "memory");   // tile 0 landed, tile 1 in flight
  __builtin_amdgcn_s_barrier();
  __builtin_amdgcn_sched_barrier(0);

  const int swx = (g ^ ((j >> 1) & 3)) << 4;             // read-side swizzle offset
  int cur = 0;
  for (int ks = 0; ks < ksteps; ++ks){
    int nxt = cur + 2; if (nxt >= 3) nxt -= 3;
    bool pf = (ks + 2 < ksteps);
    if (pf) stage(nxt, ks + 2);
    const char* La = (const char*)&abuf[cur][0][0];
    const char* Lb = (const char*)&bbuf[cur][0][0];
    bf16x8 af[8], bfr[2];
    #pragma unroll
    for (int mi = 0; mi < 8; ++mi) af[mi]  = *(const bf16x8*)(La + ((wr*128 + mi*16 + j) << 6) + swx);
    #pragma unroll
    for (int ni = 0; ni < 2; ++ni) bfr[ni] = *(const bf16x8*)(Lb + ((wc*32 + ni*16 + j) << 6) + swx);
    __builtin_amdgcn_s_setprio(1);
    #pragma unroll
    for (int mi = 0; mi < 8; ++mi)
      #pragma unroll
      for (int ni = 0; ni < 2; ++ni)
        acc[mi][ni] = __builtin_amdgcn_mfma_f32_16x16x32_bf16(af[mi], bfr[ni], acc[mi][ni], 0, 0, 0);
    __builtin_amdgcn_s_setprio(0);
    if (pf) asm volatile("s_waitcnt vmcnt(3)" ::: "memory");  // ks+1 landed; ks+2 in flight
    else    asm volatile("s_waitcnt vmcnt(0)" ::: "memory");
    __builtin_amdgcn_s_barrier();
    __builtin_amdgcn_sched_barrier(0);
    cur += 1; if (cur >= 3) cur -= 3;
  }

  #pragma unroll
  for (int mi = 0; mi < 8; ++mi){
    int row0 = m0 + wr*128 + mi*16 + g*4;
    #pragma unroll
    for (int ni = 0; ni < 2; ++ni){
      int col = n0 + wc*32 + ni*16 + j;
      float bs = bias[col];
      if (!TRANSV){
        #pragma unroll
        for (int r = 0; r < 4; ++r)
          out[(size_t)(row0 + r) * NCH + col] = f2bf((acc[mi][ni][r] + bs) * oscale);
      } else {
        int bidx = row0 >> 12, kv = row0 & (KVL_ - 1);
        int h = col >> 7, dv = col & 127;
        int c = (kv & ~31) | (((kv & 15) >> 2) << 3) | (((kv >> 4) & 1) << 2);
        us4 pk;
        #pragma unroll
        for (int r = 0; r < 4; ++r) pk[r] = f2bf(acc[mi][ni][r] + bs);
        *(us4*)&out[((size_t)(bidx * H_ + h) * DH + dv) * KVL_ + c] = pk;
      }
    }
  }
}

// ---------------- Flash attention: 4 waves x 32 q-rows, l-sum via ones-MFMA ----------------
__global__ __launch_bounds__(256, 2)
void attn_kernel(const ushort_t* __restrict__ Q, const ushort_t* __restrict__ Km,
                 const ushort_t* __restrict__ Vt, ushort_t* __restrict__ ctxp,
                 float* __restrict__ mlp){
  __shared__ __align__(16) ushort_t Kbuf[2][KVBLK][DH];   // 32 KB
  __shared__ __align__(16) ushort_t Vbuf[2][DH][KVBLK];   // 32 KB (columns pre-permuted)

  int bid = blockIdx.x;
  int xcd = bid & 7, slot = bid >> 3;
  int p   = xcd + 8 * (slot >> 2);       // 0..127 -> (bh, sp)
  int qb  = slot & 3;
  int bh  = p >> 2, sp = p & 3;
  int b = bh >> 3, h = bh & 7;

  int tid = threadIdx.x;
  int w = tid >> 6, lane = tid & 63;
  int g = lane >> 4, j = lane & 15;
  int qbase = qb * 128 + w * 32;          // wave's 32 q-rows

  bf16x8 qreg[2][4];                       // [qg][kb]: Q[qbase+qg*16+j][kb*32+g*8+e]
  #pragma unroll
  for (int qg = 0; qg < 2; ++qg){
    const ushort_t* Qb = Q + (size_t)(b * QL_ + qbase + qg * 16 + j) * NCH + h * DH + g * 8;
    #pragma unroll
    for (int kb = 0; kb < 4; ++kb) qreg[qg][kb] = *(const bf16x8*)(Qb + kb * 32);
  }

  f32x4 ctx[2][8] = {};
  f32x4 lacc[2] = {};                      // unnormalized row-sums, ctx layout (q=4g+r)
  float m_[2] = {-1e30f, -1e30f};

  const short ONEB = (short)0x3F80;        // bf16 1.0
  const bf16x8 ones = {ONEB, ONEB, ONEB, ONEB, ONEB, ONEB, ONEB, ONEB};

  const int kvbeg = sp * (KVL_ / NS);
  const char* Kg = (const char*)(Km + (size_t)b * KVL_ * NCH) + h * 256;
  const char* Vg = (const char*)(Vt + (size_t)(b * H_ + h) * DH * KVL_);

  auto stage = [&](int bi, int kv0){       // 8 gload16/thread (256 threads)
    #pragma unroll
    for (int i = 0; i < 4; ++i){
      int lin = (i * 256 + tid) * 16;
      int sw  = lin ^ (((lin >> 8) & 7) << 4);
      gload16((char*)&Kbuf[bi][0][0] + lin,
              Kg + (size_t)(kv0 + (sw >> 8)) * 2048 + (sw & 255));
    }
    #pragma unroll
    for (int i = 0; i < 4; ++i){
      int lin = (i * 256 + tid) * 16;
      int sw  = lin ^ (((lin >> 7) & 7) << 4);
      gload16((char*)&Vbuf[bi][0][0] + lin,
              Vg + (size_t)(sw >> 7) * (KVL_ * 2) + kv0 * 2 + (sw & 127));
    }
  };

  const float THR = 11.5415603f;            // 8 * log2(e)
  const int NCHUNK = (KVL_ / NS) / KVBLK;   // 16

  stage(0, kvbeg);
  __syncthreads();

  for (int c = 0; c < NCHUNK; ++c){
    int bi = c & 1;
    if (c + 1 < NCHUNK) stage(bi ^ 1, kvbeg + (c + 1) * KVBLK);

    const char* Kl = (const char*)&Kbuf[bi][0][0];
    const char* Vl = (const char*)&Vbuf[bi][0][0];

    // QK^T swapped, K-frag loaded once and shared by both q-groups
    f32x4 s[2][4] = {};
    __builtin_amdgcn_s_setprio(1);
    #pragma unroll
    for (int kf = 0; kf < 4; ++kf){
      #pragma unroll
      for (int kb = 0; kb < 4; ++kb){
        int off = (kf * 16 + j) * 256 + kb * 64 + g * 16;
        off ^= ((j & 7) << 4);
        bf16x8 kfrag = *(const bf16x8*)(Kl + off);
        s[0][kf] = __builtin_amdgcn_mfma_f32_16x16x32_bf16(kfrag, qreg[0][kb], s[0][kf], 0, 0, 0);
        s[1][kf] = __builtin_amdgcn_mfma_f32_16x16x32_bf16(kfrag, qreg[1][kb], s[1][kf], 0, 0, 0);
      }
    }
    __builtin_amdgcn_s_setprio(0);

    union { unsigned u[4]; bf16x8 v; } pa[2][2];
    #pragma unroll
    for (int qg = 0; qg < 2; ++qg){
      float t0 = fmaxf(fmaxf(s[qg][0][0], s[qg][0][1]), fmaxf(s[qg][0][2], s[qg][0][3]));
      float t1 = fmaxf(fmaxf(s[qg][1][0], s[qg][1][1]), fmaxf(s[qg][1][2], s[qg][1][3]));
      float t2 = fmaxf(fmaxf(s[qg][2][0], s[qg][2][1]), fmaxf(s[qg][2][2], s[qg][2][3]));
      float t3 = fmaxf(fmaxf(s[qg][3][0], s[qg][3][1]), fmaxf(s[qg][3][2], s[qg][3][3]));
      float pm = fmaxf(fmaxf(t0, t1), fmaxf(t2, t3));
      pm = fmaxf(pm, __shfl_xor(pm, 16));
      pm = fmaxf(pm, __shfl_xor(pm, 32));
      int ok = (pm - m_[qg] <= THR);
      if (!__all(ok)){
        float mn = fmaxf(m_[qg], pm);
        float cf = exp2f(m_[qg] - mn);
        m_[qg] = mn;
        float cfr[4];
        #pragma unroll
        for (int r = 0; r < 4; ++r) cfr[r] = __shfl(cf, g * 4 + r);
        #pragma unroll
        for (int df = 0; df < 8; ++df)
          #pragma unroll
          for (int r = 0; r < 4; ++r) ctx[qg][df][r] *= cfr[r];
        #pragma unroll
        for (int r = 0; r < 4; ++r) lacc[qg][r] *= cfr[r];
      }
      #pragma unroll
      for (int kf = 0; kf < 4; ++kf)
        #pragma unroll
        for (int r = 0; r < 4; ++r)
          s[qg][kf][r] = exp2f(s[qg][kf][r] - m_[qg]);
      #pragma unroll
      for (int kb = 0; kb < 2; ++kb){
        asm("v_cvt_pk_bf16_f32 %0, %1, %2" : "=v"(pa[qg][kb].u[0]) : "v"(s[qg][2*kb][0]),   "v"(s[qg][2*kb][1]));
        asm("v_cvt_pk_bf16_f32 %0, %1, %2" : "=v"(pa[qg][kb].u[1]) : "v"(s[qg][2*kb][2]),   "v"(s[qg][2*kb][3]));
        asm("v_cvt_pk_bf16_f32 %0, %1, %2" : "=v"(pa[qg][kb].u[2]) : "v"(s[qg][2*kb+1][0]), "v"(s[qg][2*kb+1][1]));
        asm("v_cvt_pk_bf16_f32 %0, %1, %2" : "=v"(pa[qg][kb].u[3]) : "v"(s[qg][2*kb+1][2]), "v"(s[qg][2*kb+1][3]));
      }
    }

    // PV + l-sum: V-frag loaded once, shared by both q-groups; ones-MFMA row-sums P
    __builtin_amdgcn_s_setprio(1);
    lacc[0] = __builtin_amdgcn_mfma_f32_16x16x32_bf16(pa[0][0].v, ones, lacc[0], 0, 0, 0);
    lacc[0] = __builtin_amdgcn_mfma_f32_16x16x32_bf16(pa[0][1].v, ones, lacc[0], 0, 0, 0);
    lacc[1] = __builtin_amdgcn_mfma_f32_16x16x32_bf16(pa[1][0].v, ones, lacc[1], 0, 0, 0);
    lacc[1] = __builtin_amdgcn_mfma_f32_16x16x32_bf16(pa[1][1].v, ones, lacc[1], 0, 0, 0);
    #pragma unroll
    for (int df = 0; df < 8; ++df){
      int off0 = (df * 16 + j) * 128 + g * 16;        int o0 = off0 ^ ((j & 7) << 4);
      int off1 = (df * 16 + j) * 128 + 64 + g * 16;   int o1 = off1 ^ ((j & 7) << 4);
      bf16x8 v0 = *(const bf16x8*)(Vl + o0);
      bf16x8 v1 = *(const bf16x8*)(Vl + o1);
      ctx[0][df] = __builtin_amdgcn_mfma_f32_16x16x32_bf16(pa[0][0].v, v0, ctx[0][df], 0, 0, 0);
      ctx[0][df] = __builtin_amdgcn_mfma_f32_16x16x32_bf16(pa[0][1].v, v1, ctx[0][df], 0, 0, 0);
      ctx[1][df] = __builtin_amdgcn_mfma_f32_16x16x32_bf16(pa[1][0].v, v0, ctx[1][df], 0, 0, 0);
      ctx[1][df] = __builtin_amdgcn_mfma_f32_16x16x32_bf16(pa[1][1].v, v1, ctx[1][df], 0, 0, 0);
    }
    __builtin_amdgcn_s_setprio(0);
    __syncthreads();
  }

  #pragma unroll
  for (int qg = 0; qg < 2; ++qg){
    size_t prow0 = ((size_t)sp * 32 + bh) * QL_ + qbase + qg * 16;
    #pragma unroll
    for (int r = 0; r < 4; ++r){
      ushort_t* cp = ctxp + (prow0 + g * 4 + r) * DH;
      #pragma unroll
      for (int df = 0; df < 8; ++df) cp[df * 16 + j] = f2bf(ctx[qg][df][r]);
    }
    if (j == 0){
      #pragma unroll
      for (int r = 0; r < 4; ++r)
        mlp[(prow0 + g * 4 + r) * 2 + 1] = lacc[qg][r];
    }
    if (g == 0)
      mlp[(prow0 + j) * 2] = m_[qg];
  }
}

// ---------------- Split combine: 1 wave per q-row (m in log2 domain, bf16 ctx) ----------------
__global__ __launch_bounds__(256)
void combine_kernel(const ushort_t* __restrict__ ctxp, const float* __restrict__ mlp,
                    float* __restrict__ out){
  int row = blockIdx.x * 4 + (threadIdx.x >> 6);   // (b*8+h)*512 + q
  int lane = threadIdx.x & 63;
  int b = row >> 12, h = (row >> 9) & 7, q = row & 511;
  float ms[NS], ls[NS];
  #pragma unroll
  for (int s = 0; s < NS; ++s){
    ms[s] = mlp[((size_t)(s * NROWS + row)) * 2];
    ls[s] = mlp[((size_t)(s * NROWS + row)) * 2 + 1];
  }
  float M = ms[0];
  #pragma unroll
  for (int s = 1; s < NS; ++s) M = fmaxf(M, ms[s]);
  float wgt[NS], L = 0.f;
  #pragma unroll
  for (int s = 0; s < NS; ++s){ wgt[s] = exp2f(ms[s] - M); L += ls[s] * wgt[s]; }
  float inv = 1.f / L;
  float ax = 0.f, ay = 0.f;
  #pragma unroll
  for (int s = 0; s < NS; ++s){
    unsigned pk = *(const unsigned*)(ctxp + ((size_t)(s * NROWS + row)) * DH + lane * 2);
    ax += bf2f(pk & 0xFFFFu) * wgt[s];
    ay += bf2f(pk >> 16) * wgt[s];
  }
  float* op = out + ((size_t)(b * QL_ + q)) * NCH + h * DH + lane * 2;
  op[0] = ax * inv; op[1] = ay * inv;
}

extern "C" void kernel_launch(void* const* d_in, const int* in_sizes, int n_in,
                              void* d_out, int out_size, void* d_ws, size_t ws_size,
                              hipStream_t stream){
  const float* hs   = (const float*)d_in[0];
  const float* inp  = (const float*)d_in[1];
  const float* ln1g = (const float*)d_in[2];
  const float* ln1b = (const float*)d_in[3];
  const float* ln2g = (const float*)d_in[4];
  const float* ln2b = (const float*)d_in[5];
  const float* Wq   = (const float*)d_in[6];
  const float* bq   = (const float*)d_in[7];
  const float* Wk   = (const float*)d_in[8];
  const float* bk   = (const float*)d_in[9];
  const float* Wv   = (const float*)d_in[10];
  const float* bv   = (const float*)d_in[11];

  char* ws = (char*)d_ws;
  size_t off = 0;
  auto alloc = [&](size_t bytes){ void* pp = ws + off; off += (bytes + 255) & ~255ull; return pp; };
  // persistent across phases
  ushort_t* Qm = (ushort_t*)alloc((size_t)2048 * 1024 * 2);
  ushort_t* Km = (ushort_t*)alloc((size_t)16384 * 1024 * 2);
  ushort_t* Vt = (ushort_t*)alloc((size_t)16384 * 1024 * 2);
  size_t base2 = off;
  // phase 1: LN outputs + transposed weights (dead after the GEMMs)
  ushort_t* hs_ln = (ushort_t*)alloc((size_t)2048 * 1024 * 2);
  ushort_t* in_ln = (ushort_t*)alloc((size_t)16384 * 768 * 2);
  ushort_t* Wqt   = (ushort_t*)alloc((size_t)1024 * 1024 * 2);
  ushort_t* Wkt   = (ushort_t*)alloc((size_t)1024 * 768 * 2);
  ushort_t* Wvt   = (ushort_t*)alloc((size_t)1024 * 768 * 2);
  // phase 2: attention partials (alias phase 1)
  off = base2;
  ushort_t* ctxp = (ushort_t*)alloc((size_t)NS * NROWS * DH * 2);
  float*    mlp  = (float*)alloc((size_t)NS * NROWS * 2 * 4);

  const float QSC = 0.08838834764831845f * 1.4426950408889634f;  // 1/sqrt(128)*log2(e)

  ln_kernel<1024><<<512, 256, 0, stream>>>(hs, ln1g, ln1b, hs_ln);
  ln_kernel<768><<<4096, 256, 0, stream>>>(inp, ln2g, ln2b, in_ln);
  wtrans_kernel<<<dim3(32, 32, 3), 256, 0, stream>>>(Wq, Wqt, Wk, Wkt, Wv, Wvt);
  gemm_kernel<<<dim3(16, 8), 256, 0, stream>>>(hs_ln, Wqt, bq, Qm, 2048, 1024, QSC);
  gemm256_kernel<false><<<dim3(64, 8), 512, 0, stream>>>(in_ln, Wkt, bk, Km, 16384, 768, 1.0f);
  gemm256_kernel<true ><<<dim3(64, 8), 512, 0, stream>>>(in_ln, Wvt, bv, Vt, 16384, 768, 1.0f);
  attn_kernel<<<512, 256, 0, stream>>>(Qm, Km, Vt, ctxp, mlp);
  combine_kernel<<<NROWS / 4, 256, 0, stream>>>(ctxp, mlp, (float*)d_out);
}

// Round 19
// 160.680 us; speedup vs baseline: 1.0515x; 1.0515x over previous
//
#include <hip/hip_runtime.h>
#include <hip/hip_bf16.h>
#include <stdint.h>

#define B_    4
#define QL_   512
#define KVL_  4096
#define QDIM  1024
#define KVDIM 768
#define NCH   1024
#define H_    8
#define DH    128
#define NROWS (B_ * H_ * QL_)   // 16384 partial rows
#define KVBLK 64
#define NS    4

typedef unsigned short ushort_t;
typedef __attribute__((ext_vector_type(8))) short bf16x8;
typedef __attribute__((ext_vector_type(4))) float f32x4;
typedef __attribute__((ext_vector_type(4))) unsigned short us4;

__device__ __forceinline__ ushort_t f2bf(float x){
  union { float f; unsigned u; } v; v.f = x;
  unsigned r = v.u + 0x7FFF + ((v.u >> 16) & 1);
  return (ushort_t)(r >> 16);
}

__device__ __forceinline__ float bf2f(unsigned hs){
  union { unsigned u; float f; } v; v.u = hs << 16; return v.f;
}

__device__ __forceinline__ void gload16(void* l, const void* g){
  __builtin_amdgcn_global_load_lds(
    (const __attribute__((address_space(1))) unsigned int*)g,
    (__attribute__((address_space(3))) unsigned int*)l, 16, 0, 0);
}

// ---------------- LayerNorm row (wave-per-row, no LDS, no barrier) ----------------
template<int D>
__device__ __forceinline__ void ln_row(const float* __restrict__ x, const float* __restrict__ gamma,
                                       const float* __restrict__ beta, ushort_t* __restrict__ out,
                                       int rowBlock){
  constexpr int NPT = D / 256;           // f32x4 per lane
  int w = threadIdx.x >> 6, lane = threadIdx.x & 63;
  int row = rowBlock * 4 + w;
  const f32x4* xr = (const f32x4*)(x + (size_t)row * D);
  f32x4 v[NPT];
  float s = 0.f, s2 = 0.f;
  #pragma unroll
  for (int k = 0; k < NPT; ++k){
    v[k] = xr[k * 64 + lane];
    #pragma unroll
    for (int e = 0; e < 4; ++e){ s += v[k][e]; s2 += v[k][e] * v[k][e]; }
  }
  #pragma unroll
  for (int m = 32; m; m >>= 1){ s += __shfl_xor(s, m); s2 += __shfl_xor(s2, m); }
  float mu  = s / D;
  float var = s2 / D - mu * mu;
  float rs  = rsqrtf(var + 1e-3f);
  us4* orow = (us4*)(out + (size_t)row * D);
  #pragma unroll
  for (int k = 0; k < NPT; ++k){
    f32x4 gm = ((const f32x4*)gamma)[k * 64 + lane];
    f32x4 bt = ((const f32x4*)beta)[k * 64 + lane];
    us4 o;
    #pragma unroll
    for (int e = 0; e < 4; ++e) o[e] = f2bf((v[k][e] - mu) * rs * gm[e] + bt[e]);
    orow[k * 64 + lane] = o;
  }
}

// ---------------- Fused preamble: both LNs + 3 weight transposes in one launch ----------------
// blocks [0,512): hs LN (D=1024); [512,4608): inp LN (D=768); [4608,7680): wtrans.
__global__ __launch_bounds__(256)
void pre_kernel(const float* __restrict__ hs,  const float* __restrict__ ln1g,
                const float* __restrict__ ln1b, ushort_t* __restrict__ hs_ln,
                const float* __restrict__ inp, const float* __restrict__ ln2g,
                const float* __restrict__ ln2b, ushort_t* __restrict__ in_ln,
                const float* __restrict__ Wq, ushort_t* __restrict__ Wqt,
                const float* __restrict__ Wk, ushort_t* __restrict__ Wkt,
                const float* __restrict__ Wv, ushort_t* __restrict__ Wvt){
  __shared__ float t[32][33];
  int bid = blockIdx.x;
  if (bid < 512){ ln_row<1024>(hs, ln1g, ln1b, hs_ln, bid); return; }
  if (bid < 4608){ ln_row<768>(inp, ln2g, ln2b, in_ln, bid - 512); return; }
  int zz = bid - 4608;
  int z = zz >> 10, rem = zz & 1023;
  const float* W = (z == 0) ? Wq : (z == 1) ? Wk : Wv;
  ushort_t* Wt   = (z == 0) ? Wqt : (z == 1) ? Wkt : Wvt;
  int K = (z == 0) ? 1024 : 768;
  int n0 = (rem & 31) * 32, k0 = (rem >> 5) * 32;
  if (k0 >= K) return;
  int tx = threadIdx.x & 31, ty = threadIdx.x >> 5;   // 32 x 8
  #pragma unroll
  for (int i = 0; i < 32; i += 8) t[ty + i][tx] = W[(size_t)(k0 + ty + i) * NCH + n0 + tx];
  __syncthreads();
  #pragma unroll
  for (int i = 0; i < 32; i += 8)
    Wt[(size_t)(n0 + ty + i) * K + k0 + tx] = f2bf(t[tx][ty + i]);
}

// ---------------- small GEMM (Q): 128x128 tile, 3-buffer counted-vmcnt ----------------
__global__ __launch_bounds__(256)
void gemm_kernel(const ushort_t* __restrict__ A, const ushort_t* __restrict__ Bw,
                 const float* __restrict__ bias, ushort_t* __restrict__ out,
                 int M, int K, float oscale){
  __shared__ __align__(16) ushort_t lds[3][2][4][128][8];   // 48 KB, buf = ks%3
  int tid = threadIdx.x;
  int w = tid >> 6, lane = tid & 63;
  int m0 = blockIdx.x * 128, n0 = blockIdx.y * 128;
  int wr = w >> 1, wc = w & 1;
  int g = lane >> 4, j = lane & 15;
  f32x4 acc[4][4] = {};
  const int ksteps = K / 32;
  const ushort_t* Aw  = A  + (size_t)(m0 + lane) * K + w * 8;
  const ushort_t* Bww = Bw + (size_t)(n0 + lane) * K + w * 8;

  auto stage = [&](int buf, int ks){      // 4 loads/wave
    #pragma unroll
    for (int i = 0; i < 2; ++i){
      gload16(&lds[buf][0][w][i*64][0], Aw  + (size_t)i*64*K + ks*32);
      gload16(&lds[buf][1][w][i*64][0], Bww + (size_t)i*64*K + ks*32);
    }
  };

  stage(0, 0);
  stage(1, 1);
  asm volatile("s_waitcnt vmcnt(4)" ::: "memory");
  __builtin_amdgcn_s_barrier();
  __builtin_amdgcn_sched_barrier(0);

  int cur = 0;
  for (int ks = 0; ks < ksteps; ++ks){
    int nxt = cur + 2; if (nxt >= 3) nxt -= 3;
    bool pf = (ks + 2 < ksteps);
    if (pf) stage(nxt, ks + 2);
    bf16x8 af[4], bfr[4];
    #pragma unroll
    for (int mi = 0; mi < 4; ++mi) af[mi]  = *(const bf16x8*)&lds[cur][0][g][wr*64 + mi*16 + j][0];
    #pragma unroll
    for (int ni = 0; ni < 4; ++ni) bfr[ni] = *(const bf16x8*)&lds[cur][1][g][wc*64 + ni*16 + j][0];
    __builtin_amdgcn_s_setprio(1);
    #pragma unroll
    for (int mi = 0; mi < 4; ++mi)
      #pragma unroll
      for (int ni = 0; ni < 4; ++ni)
        acc[mi][ni] = __builtin_amdgcn_mfma_f32_16x16x32_bf16(af[mi], bfr[ni], acc[mi][ni], 0, 0, 0);
    __builtin_amdgcn_s_setprio(0);
    if (pf) asm volatile("s_waitcnt vmcnt(4)" ::: "memory");
    else    asm volatile("s_waitcnt vmcnt(0)" ::: "memory");
    __builtin_amdgcn_s_barrier();
    __builtin_amdgcn_sched_barrier(0);
    cur += 1; if (cur >= 3) cur -= 3;
  }

  #pragma unroll
  for (int mi = 0; mi < 4; ++mi){
    int row0 = m0 + wr*64 + mi*16 + g*4;
    #pragma unroll
    for (int ni = 0; ni < 4; ++ni){
      int col = n0 + wc*64 + ni*16 + j;
      float bs = bias[col];
      #pragma unroll
      for (int r = 0; r < 4; ++r)
        out[(size_t)(row0 + r) * NCH + col] = f2bf((acc[mi][ni][r] + bs) * oscale);
    }
  }
}

// ---------------- big GEMM (K/V): 256x256 tile, swizzled row-major LDS (r16 best) ----------------
template<bool TRANSV>
__global__ __launch_bounds__(512, 2)
void gemm256_kernel(const ushort_t* __restrict__ A, const ushort_t* __restrict__ Bw,
                    const float* __restrict__ bias, ushort_t* __restrict__ out,
                    int M, int K, float oscale){
  __shared__ __align__(16) ushort_t lds[3][2][256][32];   // 96 KB, buf = ks%3
  int tid = threadIdx.x;
  int w = tid >> 6, lane = tid & 63;
  int m0 = blockIdx.x * 256, n0 = blockIdx.y * 256;
  int wr = w >> 2, wc = w & 3;
  int g = lane >> 4, j = lane & 15;
  f32x4 acc[8][4] = {};
  const int ksteps = K / 32;
  int srow = tid >> 2;
  int cg = (tid & 3) ^ ((tid >> 3) & 3);                 // inverse-swizzled source col-group
  const ushort_t* Asrc = A  + (size_t)(m0 + srow) * K + cg * 8;
  const ushort_t* Bsrc = Bw + (size_t)(n0 + srow) * K + cg * 8;

  auto stage = [&](int buf, int ks){      // 4 gload16/thread, linear LDS dest
    char* la = (char*)&lds[buf][0][0][0] + tid * 16;
    char* lb = (char*)&lds[buf][1][0][0] + tid * 16;
    #pragma unroll
    for (int i = 0; i < 2; ++i){
      gload16(la + i*8192, Asrc + (size_t)(i*128)*K + ks*32);
      gload16(lb + i*8192, Bsrc + (size_t)(i*128)*K + ks*32);
    }
  };

  stage(0, 0);
  stage(1, 1);
  asm volatile("s_waitcnt vmcnt(4)" ::: "memory");
  __builtin_amdgcn_s_barrier();
  __builtin_amdgcn_sched_barrier(0);

  const int swx = (g ^ ((j >> 1) & 3)) << 4;             // read-side swizzle offset
  int cur = 0;
  for (int ks = 0; ks < ksteps; ++ks){
    int nxt = cur + 2; if (nxt >= 3) nxt -= 3;
    bool pf = (ks + 2 < ksteps);
    if (pf) stage(nxt, ks + 2);
    const char* La = (const char*)&lds[cur][0][0][0];
    const char* Lb = (const char*)&lds[cur][1][0][0];
    bf16x8 af[8], bfr[4];
    #pragma unroll
    for (int mi = 0; mi < 8; ++mi) af[mi]  = *(const bf16x8*)(La + ((wr*128 + mi*16 + j) << 6) + swx);
    #pragma unroll
    for (int ni = 0; ni < 4; ++ni) bfr[ni] = *(const bf16x8*)(Lb + ((wc*64  + ni*16 + j) << 6) + swx);
    __builtin_amdgcn_s_setprio(1);
    #pragma unroll
    for (int mi = 0; mi < 8; ++mi)
      #pragma unroll
      for (int ni = 0; ni < 4; ++ni)
        acc[mi][ni] = __builtin_amdgcn_mfma_f32_16x16x32_bf16(af[mi], bfr[ni], acc[mi][ni], 0, 0, 0);
    __builtin_amdgcn_s_setprio(0);
    if (pf) asm volatile("s_waitcnt vmcnt(4)" ::: "memory");
    else    asm volatile("s_waitcnt vmcnt(0)" ::: "memory");
    __builtin_amdgcn_s_barrier();
    __builtin_amdgcn_sched_barrier(0);
    cur += 1; if (cur >= 3) cur -= 3;
  }

  #pragma unroll
  for (int mi = 0; mi < 8; ++mi){
    int row0 = m0 + wr*128 + mi*16 + g*4;
    #pragma unroll
    for (int ni = 0; ni < 4; ++ni){
      int col = n0 + wc*64 + ni*16 + j;
      float bs = bias[col];
      if (!TRANSV){
        #pragma unroll
        for (int r = 0; r < 4; ++r)
          out[(size_t)(row0 + r) * NCH + col] = f2bf((acc[mi][ni][r] + bs) * oscale);
      } else {
        int bidx = row0 >> 12, kv = row0 & (KVL_ - 1);
        int h = col >> 7, dv = col & 127;
        int c = (kv & ~31) | (((kv & 15) >> 2) << 3) | (((kv >> 4) & 1) << 2);
        us4 pk;
        #pragma unroll
        for (int r = 0; r < 4; ++r) pk[r] = f2bf(acc[mi][ni][r] + bs);
        *(us4*)&out[((size_t)(bidx * H_ + h) * DH + dv) * KVL_ + c] = pk;
      }
    }
  }
}

// ---------------- Flash attention: 4 waves x 32 q-rows, l-sum via ones-MFMA ----------------
__global__ __launch_bounds__(256, 2)
void attn_kernel(const ushort_t* __restrict__ Q, const ushort_t* __restrict__ Km,
                 const ushort_t* __restrict__ Vt, ushort_t* __restrict__ ctxp,
                 float* __restrict__ mlp){
  __shared__ __align__(16) ushort_t Kbuf[2][KVBLK][DH];   // 32 KB
  __shared__ __align__(16) ushort_t Vbuf[2][DH][KVBLK];   // 32 KB (columns pre-permuted)

  int bid = blockIdx.x;
  int xcd = bid & 7, slot = bid >> 3;
  int p   = xcd + 8 * (slot >> 2);       // 0..127 -> (bh, sp)
  int qb  = slot & 3;
  int bh  = p >> 2, sp = p & 3;
  int b = bh >> 3, h = bh & 7;

  int tid = threadIdx.x;
  int w = tid >> 6, lane = tid & 63;
  int g = lane >> 4, j = lane & 15;
  int qbase = qb * 128 + w * 32;          // wave's 32 q-rows

  bf16x8 qreg[2][4];                       // [qg][kb]: Q[qbase+qg*16+j][kb*32+g*8+e]
  #pragma unroll
  for (int qg = 0; qg < 2; ++qg){
    const ushort_t* Qb = Q + (size_t)(b * QL_ + qbase + qg * 16 + j) * NCH + h * DH + g * 8;
    #pragma unroll
    for (int kb = 0; kb < 4; ++kb) qreg[qg][kb] = *(const bf16x8*)(Qb + kb * 32);
  }

  f32x4 ctx[2][8] = {};
  f32x4 lacc[2] = {};                      // unnormalized row-sums, ctx layout (q=4g+r)
  float m_[2] = {-1e30f, -1e30f};

  const short ONEB = (short)0x3F80;        // bf16 1.0
  const bf16x8 ones = {ONEB, ONEB, ONEB, ONEB, ONEB, ONEB, ONEB, ONEB};

  const int kvbeg = sp * (KVL_ / NS);
  const char* Kg = (const char*)(Km + (size_t)b * KVL_ * NCH) + h * 256;
  const char* Vg = (const char*)(Vt + (size_t)(b * H_ + h) * DH * KVL_);

  auto stage = [&](int bi, int kv0){       // 8 gload16/thread (256 threads)
    #pragma unroll
    for (int i = 0; i < 4; ++i){
      int lin = (i * 256 + tid) * 16;
      int sw  = lin ^ (((lin >> 8) & 7) << 4);
      gload16((char*)&Kbuf[bi][0][0] + lin,
              Kg + (size_t)(kv0 + (sw >> 8)) * 2048 + (sw & 255));
    }
    #pragma unroll
    for (int i = 0; i < 4; ++i){
      int lin = (i * 256 + tid) * 16;
      int sw  = lin ^ (((lin >> 7) & 7) << 4);
      gload16((char*)&Vbuf[bi][0][0] + lin,
              Vg + (size_t)(sw >> 7) * (KVL_ * 2) + kv0 * 2 + (sw & 127));
    }
  };

  const float THR = 11.5415603f;            // 8 * log2(e)
  const int NCHUNK = (KVL_ / NS) / KVBLK;   // 16

  stage(0, kvbeg);
  __syncthreads();

  for (int c = 0; c < NCHUNK; ++c){
    int bi = c & 1;
    if (c + 1 < NCHUNK) stage(bi ^ 1, kvbeg + (c + 1) * KVBLK);

    const char* Kl = (const char*)&Kbuf[bi][0][0];
    const char* Vl = (const char*)&Vbuf[bi][0][0];

    // QK^T swapped, K-frag loaded once and shared by both q-groups
    f32x4 s[2][4] = {};
    __builtin_amdgcn_s_setprio(1);
    #pragma unroll
    for (int kf = 0; kf < 4; ++kf){
      #pragma unroll
      for (int kb = 0; kb < 4; ++kb){
        int off = (kf * 16 + j) * 256 + kb * 64 + g * 16;
        off ^= ((j & 7) << 4);
        bf16x8 kfrag = *(const bf16x8*)(Kl + off);
        s[0][kf] = __builtin_amdgcn_mfma_f32_16x16x32_bf16(kfrag, qreg[0][kb], s[0][kf], 0, 0, 0);
        s[1][kf] = __builtin_amdgcn_mfma_f32_16x16x32_bf16(kfrag, qreg[1][kb], s[1][kf], 0, 0, 0);
      }
    }
    __builtin_amdgcn_s_setprio(0);

    union { unsigned u[4]; bf16x8 v; } pa[2][2];
    #pragma unroll
    for (int qg = 0; qg < 2; ++qg){
      float t0 = fmaxf(fmaxf(s[qg][0][0], s[qg][0][1]), fmaxf(s[qg][0][2], s[qg][0][3]));
      float t1 = fmaxf(fmaxf(s[qg][1][0], s[qg][1][1]), fmaxf(s[qg][1][2], s[qg][1][3]));
      float t2 = fmaxf(fmaxf(s[qg][2][0], s[qg][2][1]), fmaxf(s[qg][2][2], s[qg][2][3]));
      float t3 = fmaxf(fmaxf(s[qg][3][0], s[qg][3][1]), fmaxf(s[qg][3][2], s[qg][3][3]));
      float pm = fmaxf(fmaxf(t0, t1), fmaxf(t2, t3));
      pm = fmaxf(pm, __shfl_xor(pm, 16));
      pm = fmaxf(pm, __shfl_xor(pm, 32));
      int ok = (pm - m_[qg] <= THR);
      if (!__all(ok)){
        float mn = fmaxf(m_[qg], pm);
        float cf = exp2f(m_[qg] - mn);
        m_[qg] = mn;
        float cfr[4];
        #pragma unroll
        for (int r = 0; r < 4; ++r) cfr[r] = __shfl(cf, g * 4 + r);
        #pragma unroll
        for (int df = 0; df < 8; ++df)
          #pragma unroll
          for (int r = 0; r < 4; ++r) ctx[qg][df][r] *= cfr[r];
        #pragma unroll
        for (int r = 0; r < 4; ++r) lacc[qg][r] *= cfr[r];
      }
      #pragma unroll
      for (int kf = 0; kf < 4; ++kf)
        #pragma unroll
        for (int r = 0; r < 4; ++r)
          s[qg][kf][r] = exp2f(s[qg][kf][r] - m_[qg]);
      #pragma unroll
      for (int kb = 0; kb < 2; ++kb){
        asm("v_cvt_pk_bf16_f32 %0, %1, %2" : "=v"(pa[qg][kb].u[0]) : "v"(s[qg][2*kb][0]),   "v"(s[qg][2*kb][1]));
        asm("v_cvt_pk_bf16_f32 %0, %1, %2" : "=v"(pa[qg][kb].u[1]) : "v"(s[qg][2*kb][2]),   "v"(s[qg][2*kb][3]));
        asm("v_cvt_pk_bf16_f32 %0, %1, %2" : "=v"(pa[qg][kb].u[2]) : "v"(s[qg][2*kb+1][0]), "v"(s[qg][2*kb+1][1]));
        asm("v_cvt_pk_bf16_f32 %0, %1, %2" : "=v"(pa[qg][kb].u[3]) : "v"(s[qg][2*kb+1][2]), "v"(s[qg][2*kb+1][3]));
      }
    }

    // PV + l-sum: V-frag loaded once, shared by both q-groups; ones-MFMA row-sums P
    __builtin_amdgcn_s_setprio(1);
    lacc[0] = __builtin_amdgcn_mfma_f32_16x16x32_bf16(pa[0][0].v, ones, lacc[0], 0, 0, 0);
    lacc[0] = __builtin_amdgcn_mfma_f32_16x16x32_bf16(pa[0][1].v, ones, lacc[0], 0, 0, 0);
    lacc[1] = __builtin_amdgcn_mfma_f32_16x16x32_bf16(pa[1][0].v, ones, lacc[1], 0, 0, 0);
    lacc[1] = __builtin_amdgcn_mfma_f32_16x16x32_bf16(pa[1][1].v, ones, lacc[1], 0, 0, 0);
    #pragma unroll
    for (int df = 0; df < 8; ++df){
      int off0 = (df * 16 + j) * 128 + g * 16;        int o0 = off0 ^ ((j & 7) << 4);
      int off1 = (df * 16 + j) * 128 + 64 + g * 16;   int o1 = off1 ^ ((j & 7) << 4);
      bf16x8 v0 = *(const bf16x8*)(Vl + o0);
      bf16x8 v1 = *(const bf16x8*)(Vl + o1);
      ctx[0][df] = __builtin_amdgcn_mfma_f32_16x16x32_bf16(pa[0][0].v, v0, ctx[0][df], 0, 0, 0);
      ctx[0][df] = __builtin_amdgcn_mfma_f32_16x16x32_bf16(pa[0][1].v, v1, ctx[0][df], 0, 0, 0);
      ctx[1][df] = __builtin_amdgcn_mfma_f32_16x16x32_bf16(pa[1][0].v, v0, ctx[1][df], 0, 0, 0);
      ctx[1][df] = __builtin_amdgcn_mfma_f32_16x16x32_bf16(pa[1][1].v, v1, ctx[1][df], 0, 0, 0);
    }
    __builtin_amdgcn_s_setprio(0);
    __syncthreads();
  }

  #pragma unroll
  for (int qg = 0; qg < 2; ++qg){
    size_t prow0 = ((size_t)sp * 32 + bh) * QL_ + qbase + qg * 16;
    #pragma unroll
    for (int r = 0; r < 4; ++r){
      ushort_t* cp = ctxp + (prow0 + g * 4 + r) * DH;
      #pragma unroll
      for (int df = 0; df < 8; ++df) cp[df * 16 + j] = f2bf(ctx[qg][df][r]);
    }
    if (j == 0){
      #pragma unroll
      for (int r = 0; r < 4; ++r)
        mlp[(prow0 + g * 4 + r) * 2 + 1] = lacc[qg][r];
    }
    if (g == 0)
      mlp[(prow0 + j) * 2] = m_[qg];
  }
}

// ---------------- Split combine: 1 wave per q-row (m in log2 domain, bf16 ctx) ----------------
__global__ __launch_bounds__(256)
void combine_kernel(const ushort_t* __restrict__ ctxp, const float* __restrict__ mlp,
                    float* __restrict__ out){
  int row = blockIdx.x * 4 + (threadIdx.x >> 6);   // (b*8+h)*512 + q
  int lane = threadIdx.x & 63;
  int b = row >> 12, h = (row >> 9) & 7, q = row & 511;
  float ms[NS], ls[NS];
  #pragma unroll
  for (int s = 0; s < NS; ++s){
    ms[s] = mlp[((size_t)(s * NROWS + row)) * 2];
    ls[s] = mlp[((size_t)(s * NROWS + row)) * 2 + 1];
  }
  float M = ms[0];
  #pragma unroll
  for (int s = 1; s < NS; ++s) M = fmaxf(M, ms[s]);
  float wgt[NS], L = 0.f;
  #pragma unroll
  for (int s = 0; s < NS; ++s){ wgt[s] = exp2f(ms[s] - M); L += ls[s] * wgt[s]; }
  float inv = 1.f / L;
  float ax = 0.f, ay = 0.f;
  #pragma unroll
  for (int s = 0; s < NS; ++s){
    unsigned pk = *(const unsigned*)(ctxp + ((size_t)(s * NROWS + row)) * DH + lane * 2);
    ax += bf2f(pk & 0xFFFFu) * wgt[s];
    ay += bf2f(pk >> 16) * wgt[s];
  }
  float* op = out + ((size_t)(b * QL_ + q)) * NCH + h * DH + lane * 2;
  op[0] = ax * inv; op[1] = ay * inv;
}

extern "C" void kernel_launch(void* const* d_in, const int* in_sizes, int n_in,
                              void* d_out, int out_size, void* d_ws, size_t ws_size,
                              hipStream_t stream){
  const float* hs   = (const float*)d_in[0];
  const float* inp  = (const float*)d_in[1];
  const float* ln1g = (const float*)d_in[2];
  const float* ln1b = (const float*)d_in[3];
  const float* ln2g = (const float*)d_in[4];
  const float* ln2b = (const float*)d_in[5];
  const float* Wq   = (const float*)d_in[6];
  const float* bq   = (const float*)d_in[7];
  const float* Wk   = (const float*)d_in[8];
  const float* bk   = (const float*)d_in[9];
  const float* Wv   = (const float*)d_in[10];
  const float* bv   = (const float*)d_in[11];

  char* ws = (char*)d_ws;
  size_t off = 0;
  auto alloc = [&](size_t bytes){ void* pp = ws + off; off += (bytes + 255) & ~255ull; return pp; };
  // persistent across phases
  ushort_t* Qm = (ushort_t*)alloc((size_t)2048 * 1024 * 2);
  ushort_t* Km = (ushort_t*)alloc((size_t)16384 * 1024 * 2);
  ushort_t* Vt = (ushort_t*)alloc((size_t)16384 * 1024 * 2);
  size_t base2 = off;
  // phase 1: LN outputs + transposed weights (dead after the GEMMs)
  ushort_t* hs_ln = (ushort_t*)alloc((size_t)2048 * 1024 * 2);
  ushort_t* in_ln = (ushort_t*)alloc((size_t)16384 * 768 * 2);
  ushort_t* Wqt   = (ushort_t*)alloc((size_t)1024 * 1024 * 2);
  ushort_t* Wkt   = (ushort_t*)alloc((size_t)1024 * 768 * 2);
  ushort_t* Wvt   = (ushort_t*)alloc((size_t)1024 * 768 * 2);
  // phase 2: attention partials (alias phase 1)
  off = base2;
  ushort_t* ctxp = (ushort_t*)alloc((size_t)NS * NROWS * DH * 2);
  float*    mlp  = (float*)alloc((size_t)NS * NROWS * 2 * 4);

  const float QSC = 0.08838834764831845f * 1.4426950408889634f;  // 1/sqrt(128)*log2(e)

  pre_kernel<<<7680, 256, 0, stream>>>(hs, ln1g, ln1b, hs_ln, inp, ln2g, ln2b, in_ln,
                                       Wq, Wqt, Wk, Wkt, Wv, Wvt);
  gemm_kernel<<<dim3(16, 8), 256, 0, stream>>>(hs_ln, Wqt, bq, Qm, 2048, 1024, QSC);
  gemm256_kernel<false><<<dim3(64, 4), 512, 0, stream>>>(in_ln, Wkt, bk, Km, 16384, 768, 1.0f);
  gemm256_kernel<true ><<<dim3(64, 4), 512, 0, stream>>>(in_ln, Wvt, bv, Vt, 16384, 768, 1.0f);
  attn_kernel<<<512, 256, 0, stream>>>(Qm, Km, Vt, ctxp, mlp);
  combine_kernel<<<NROWS / 4, 256, 0, stream>>>(ctxp, mlp, (float*)d_out);
}

// Round 21
// 159.427 us; speedup vs baseline: 1.0598x; 1.0079x over previous
//
#include <hip/hip_runtime.h>
#include <hip/hip_bf16.h>
#include <stdint.h>

#define B_    4
#define QL_   512
#define KVL_  4096
#define QDIM  1024
#define KVDIM 768
#define NCH   1024
#define H_    8
#define DH    128
#define NROWS (B_ * H_ * QL_)   // 16384 partial rows
#define KVBLK 64
#define NS    4

typedef unsigned short ushort_t;
typedef __attribute__((ext_vector_type(8))) short bf16x8;
typedef __attribute__((ext_vector_type(4))) float f32x4;
typedef __attribute__((ext_vector_type(4))) unsigned short us4;

__device__ __forceinline__ ushort_t f2bf(float x){
  union { float f; unsigned u; } v; v.f = x;
  unsigned r = v.u + 0x7FFF + ((v.u >> 16) & 1);
  return (ushort_t)(r >> 16);
}

__device__ __forceinline__ float bf2f(unsigned hs){
  union { unsigned u; float f; } v; v.u = hs << 16; return v.f;
}

__device__ __forceinline__ void gload16(void* l, const void* g){
  __builtin_amdgcn_global_load_lds(
    (const __attribute__((address_space(1))) unsigned int*)g,
    (__attribute__((address_space(3))) unsigned int*)l, 16, 0, 0);
}

// ---------------- LayerNorm row (wave-per-row, no LDS, no barrier) ----------------
template<int D>
__device__ __forceinline__ void ln_row(const float* __restrict__ x, const float* __restrict__ gamma,
                                       const float* __restrict__ beta, ushort_t* __restrict__ out,
                                       int rowBlock){
  constexpr int NPT = D / 256;           // f32x4 per lane
  int w = threadIdx.x >> 6, lane = threadIdx.x & 63;
  int row = rowBlock * 4 + w;
  const f32x4* xr = (const f32x4*)(x + (size_t)row * D);
  f32x4 v[NPT];
  float s = 0.f, s2 = 0.f;
  #pragma unroll
  for (int k = 0; k < NPT; ++k){
    v[k] = xr[k * 64 + lane];
    #pragma unroll
    for (int e = 0; e < 4; ++e){ s += v[k][e]; s2 += v[k][e] * v[k][e]; }
  }
  #pragma unroll
  for (int m = 32; m; m >>= 1){ s += __shfl_xor(s, m); s2 += __shfl_xor(s2, m); }
  float mu  = s / D;
  float var = s2 / D - mu * mu;
  float rs  = rsqrtf(var + 1e-3f);
  us4* orow = (us4*)(out + (size_t)row * D);
  #pragma unroll
  for (int k = 0; k < NPT; ++k){
    f32x4 gm = ((const f32x4*)gamma)[k * 64 + lane];
    f32x4 bt = ((const f32x4*)beta)[k * 64 + lane];
    us4 o;
    #pragma unroll
    for (int e = 0; e < 4; ++e) o[e] = f2bf((v[k][e] - mu) * rs * gm[e] + bt[e]);
    orow[k * 64 + lane] = o;
  }
}

// ---------------- Fused preamble: both LNs + 3 weight transposes in one launch ----------------
// blocks [0,512): hs LN (D=1024); [512,4608): inp LN (D=768); [4608,7680): wtrans.
__global__ __launch_bounds__(256)
void pre_kernel(const float* __restrict__ hs,  const float* __restrict__ ln1g,
                const float* __restrict__ ln1b, ushort_t* __restrict__ hs_ln,
                const float* __restrict__ inp, const float* __restrict__ ln2g,
                const float* __restrict__ ln2b, ushort_t* __restrict__ in_ln,
                const float* __restrict__ Wq, ushort_t* __restrict__ Wqt,
                const float* __restrict__ Wk, ushort_t* __restrict__ Wkt,
                const float* __restrict__ Wv, ushort_t* __restrict__ Wvt){
  __shared__ float t[32][33];
  int bid = blockIdx.x;
  if (bid < 512){ ln_row<1024>(hs, ln1g, ln1b, hs_ln, bid); return; }
  if (bid < 4608){ ln_row<768>(inp, ln2g, ln2b, in_ln, bid - 512); return; }
  int zz = bid - 4608;
  int z = zz >> 10, rem = zz & 1023;
  const float* W = (z == 0) ? Wq : (z == 1) ? Wk : Wv;
  ushort_t* Wt   = (z == 0) ? Wqt : (z == 1) ? Wkt : Wvt;
  int K = (z == 0) ? 1024 : 768;
  int n0 = (rem & 31) * 32, k0 = (rem >> 5) * 32;
  if (k0 >= K) return;
  int tx = threadIdx.x & 31, ty = threadIdx.x >> 5;   // 32 x 8
  #pragma unroll
  for (int i = 0; i < 32; i += 8) t[ty + i][tx] = W[(size_t)(k0 + ty + i) * NCH + n0 + tx];
  __syncthreads();
  #pragma unroll
  for (int i = 0; i < 32; i += 8)
    Wt[(size_t)(n0 + ty + i) * K + k0 + tx] = f2bf(t[tx][ty + i]);
}

// ---------------- small GEMM (Q): 128x128 tile, 3-buffer counted-vmcnt ----------------
__global__ __launch_bounds__(256)
void gemm_kernel(const ushort_t* __restrict__ A, const ushort_t* __restrict__ Bw,
                 const float* __restrict__ bias, ushort_t* __restrict__ out,
                 int M, int K, float oscale){
  __shared__ __align__(16) ushort_t lds[3][2][4][128][8];   // 48 KB, buf = ks%3
  int tid = threadIdx.x;
  int w = tid >> 6, lane = tid & 63;
  int m0 = blockIdx.x * 128, n0 = blockIdx.y * 128;
  int wr = w >> 1, wc = w & 1;
  int g = lane >> 4, j = lane & 15;
  f32x4 acc[4][4] = {};
  const int ksteps = K / 32;
  const ushort_t* Aw  = A  + (size_t)(m0 + lane) * K + w * 8;
  const ushort_t* Bww = Bw + (size_t)(n0 + lane) * K + w * 8;

  auto stage = [&](int buf, int ks){      // 4 loads/wave
    #pragma unroll
    for (int i = 0; i < 2; ++i){
      gload16(&lds[buf][0][w][i*64][0], Aw  + (size_t)i*64*K + ks*32);
      gload16(&lds[buf][1][w][i*64][0], Bww + (size_t)i*64*K + ks*32);
    }
  };

  stage(0, 0);
  stage(1, 1);
  asm volatile("s_waitcnt vmcnt(4)" ::: "memory");
  __builtin_amdgcn_s_barrier();
  __builtin_amdgcn_sched_barrier(0);

  int cur = 0;
  for (int ks = 0; ks < ksteps; ++ks){
    int nxt = cur + 2; if (nxt >= 3) nxt -= 3;
    bool pf = (ks + 2 < ksteps);
    if (pf) stage(nxt, ks + 2);
    bf16x8 af[4], bfr[4];
    #pragma unroll
    for (int mi = 0; mi < 4; ++mi) af[mi]  = *(const bf16x8*)&lds[cur][0][g][wr*64 + mi*16 + j][0];
    #pragma unroll
    for (int ni = 0; ni < 4; ++ni) bfr[ni] = *(const bf16x8*)&lds[cur][1][g][wc*64 + ni*16 + j][0];
    __builtin_amdgcn_s_setprio(1);
    #pragma unroll
    for (int mi = 0; mi < 4; ++mi)
      #pragma unroll
      for (int ni = 0; ni < 4; ++ni)
        acc[mi][ni] = __builtin_amdgcn_mfma_f32_16x16x32_bf16(af[mi], bfr[ni], acc[mi][ni], 0, 0, 0);
    __builtin_amdgcn_s_setprio(0);
    if (pf) asm volatile("s_waitcnt vmcnt(4)" ::: "memory");
    else    asm volatile("s_waitcnt vmcnt(0)" ::: "memory");
    __builtin_amdgcn_s_barrier();
    __builtin_amdgcn_sched_barrier(0);
    cur += 1; if (cur >= 3) cur -= 3;
  }

  #pragma unroll
  for (int mi = 0; mi < 4; ++mi){
    int row0 = m0 + wr*64 + mi*16 + g*4;
    #pragma unroll
    for (int ni = 0; ni < 4; ++ni){
      int col = n0 + wc*64 + ni*16 + j;
      float bs = bias[col];
      #pragma unroll
      for (int r = 0; r < 4; ++r)
        out[(size_t)(row0 + r) * NCH + col] = f2bf((acc[mi][ni][r] + bs) * oscale);
    }
  }
}

// ---------------- big GEMM (K/V): 256x256 tile, swizzled row-major LDS ----------------
// !TRANSV epilogue: wave-private LDS transpose -> full-line 64B coalesced stores.
template<bool TRANSV>
__global__ __launch_bounds__(512, 2)
void gemm256_kernel(const ushort_t* __restrict__ A, const ushort_t* __restrict__ Bw,
                    const float* __restrict__ bias, ushort_t* __restrict__ out,
                    int M, int K, float oscale){
  __shared__ __align__(16) ushort_t lds[3][2][256][32];   // 96 KB, buf = ks%3
  int tid = threadIdx.x;
  int w = tid >> 6, lane = tid & 63;
  int m0 = blockIdx.x * 256, n0 = blockIdx.y * 256;
  int wr = w >> 2, wc = w & 3;
  int g = lane >> 4, j = lane & 15;
  f32x4 acc[8][4] = {};
  const int ksteps = K / 32;
  int srow = tid >> 2;
  int cg = (tid & 3) ^ ((tid >> 3) & 3);                 // inverse-swizzled source col-group
  const ushort_t* Asrc = A  + (size_t)(m0 + srow) * K + cg * 8;
  const ushort_t* Bsrc = Bw + (size_t)(n0 + srow) * K + cg * 8;

  auto stage = [&](int buf, int ks){      // 4 gload16/thread, linear LDS dest
    char* la = (char*)&lds[buf][0][0][0] + tid * 16;
    char* lb = (char*)&lds[buf][1][0][0] + tid * 16;
    #pragma unroll
    for (int i = 0; i < 2; ++i){
      gload16(la + i*8192, Asrc + (size_t)(i*128)*K + ks*32);
      gload16(lb + i*8192, Bsrc + (size_t)(i*128)*K + ks*32);
    }
  };

  stage(0, 0);
  stage(1, 1);
  asm volatile("s_waitcnt vmcnt(4)" ::: "memory");
  __builtin_amdgcn_s_barrier();
  __builtin_amdgcn_sched_barrier(0);

  const int swx = (g ^ ((j >> 1) & 3)) << 4;             // read-side swizzle offset
  int cur = 0;
  for (int ks = 0; ks < ksteps; ++ks){
    int nxt = cur + 2; if (nxt >= 3) nxt -= 3;
    bool pf = (ks + 2 < ksteps);
    if (pf) stage(nxt, ks + 2);
    const char* La = (const char*)&lds[cur][0][0][0];
    const char* Lb = (const char*)&lds[cur][1][0][0];
    bf16x8 af[8], bfr[4];
    #pragma unroll
    for (int mi = 0; mi < 8; ++mi) af[mi]  = *(const bf16x8*)(La + ((wr*128 + mi*16 + j) << 6) + swx);
    #pragma unroll
    for (int ni = 0; ni < 4; ++ni) bfr[ni] = *(const bf16x8*)(Lb + ((wc*64  + ni*16 + j) << 6) + swx);
    __builtin_amdgcn_s_setprio(1);
    #pragma unroll
    for (int mi = 0; mi < 8; ++mi)
      #pragma unroll
      for (int ni = 0; ni < 4; ++ni)
        acc[mi][ni] = __builtin_amdgcn_mfma_f32_16x16x32_bf16(af[mi], bfr[ni], acc[mi][ni], 0, 0, 0);
    __builtin_amdgcn_s_setprio(0);
    if (pf) asm volatile("s_waitcnt vmcnt(4)" ::: "memory");
    else    asm volatile("s_waitcnt vmcnt(0)" ::: "memory");
    __builtin_amdgcn_s_barrier();
    __builtin_amdgcn_sched_barrier(0);
    cur += 1; if (cur >= 3) cur -= 3;
  }

  if (!TRANSV){
    // wave-private 2KB slice of the (now dead) staging LDS; XOR-swizzled (bits 3-5 of
    // column index) so a logical 8-run stays physically contiguous. Two b128 reads per
    // mi cover the full 16x64 tile (rows hh*8+rr, cols ck*8..ck*8+7).
    ushort_t* wlds = (ushort_t*)&lds[0][0][0][0] + w * 1024;
    int rr = lane >> 3, ck = lane & 7;     // 8 rows x 8 col-groups per read
    #pragma unroll
    for (int mi = 0; mi < 8; ++mi){
      int row0 = m0 + wr*128 + mi*16;
      #pragma unroll
      for (int ni = 0; ni < 4; ++ni){
        int c = ni*16 + j;                 // col within the wave's 64-wide stripe
        float bs = bias[n0 + wc*64 + c];
        #pragma unroll
        for (int r = 0; r < 4; ++r){
          int row = g*4 + r;
          wlds[(row*64 + c) ^ ((row & 7) << 3)] = f2bf((acc[mi][ni][r] + bs) * oscale);
        }
      }
      asm volatile("s_waitcnt lgkmcnt(0)" ::: "memory");
      __builtin_amdgcn_sched_barrier(0);
      #pragma unroll
      for (int hh = 0; hh < 2; ++hh){
        int row = hh*8 + rr;
        bf16x8 pk = *(const bf16x8*)&wlds[(row*64 + ck*8) ^ ((row & 7) << 3)];
        *(bf16x8*)&out[(size_t)(row0 + row) * NCH + n0 + wc*64 + ck*8] = pk;
      }
      asm volatile("s_waitcnt lgkmcnt(0)" ::: "memory");   // reads done before next mi overwrites
      __builtin_amdgcn_sched_barrier(0);
    }
  } else {
    #pragma unroll
    for (int mi = 0; mi < 8; ++mi){
      int row0 = m0 + wr*128 + mi*16 + g*4;
      #pragma unroll
      for (int ni = 0; ni < 4; ++ni){
        int col = n0 + wc*64 + ni*16 + j;
        float bs = bias[col];
        int bidx = row0 >> 12, kv = row0 & (KVL_ - 1);
        int h = col >> 7, dv = col & 127;
        int c = (kv & ~31) | (((kv & 15) >> 2) << 3) | (((kv >> 4) & 1) << 2);
        us4 pk;
        #pragma unroll
        for (int r = 0; r < 4; ++r) pk[r] = f2bf(acc[mi][ni][r] + bs);
        *(us4*)&out[((size_t)(bidx * H_ + h) * DH + dv) * KVL_ + c] = pk;
      }
    }
  }
}

// ---------------- Flash attention: 4 waves x 32 q-rows, l-sum via ones-MFMA ----------------
__global__ __launch_bounds__(256, 2)
void attn_kernel(const ushort_t* __restrict__ Q, const ushort_t* __restrict__ Km,
                 const ushort_t* __restrict__ Vt, ushort_t* __restrict__ ctxp,
                 float* __restrict__ mlp){
  __shared__ __align__(16) ushort_t Kbuf[2][KVBLK][DH];   // 32 KB
  __shared__ __align__(16) ushort_t Vbuf[2][DH][KVBLK];   // 32 KB (columns pre-permuted)

  int bid = blockIdx.x;
  int xcd = bid & 7, slot = bid >> 3;
  int p   = xcd + 8 * (slot >> 2);       // 0..127 -> (bh, sp)
  int qb  = slot & 3;
  int bh  = p >> 2, sp = p & 3;
  int b = bh >> 3, h = bh & 7;

  int tid = threadIdx.x;
  int w = tid >> 6, lane = tid & 63;
  int g = lane >> 4, j = lane & 15;
  int qbase = qb * 128 + w * 32;          // wave's 32 q-rows

  bf16x8 qreg[2][4];                       // [qg][kb]: Q[qbase+qg*16+j][kb*32+g*8+e]
  #pragma unroll
  for (int qg = 0; qg < 2; ++qg){
    const ushort_t* Qb = Q + (size_t)(b * QL_ + qbase + qg * 16 + j) * NCH + h * DH + g * 8;
    #pragma unroll
    for (int kb = 0; kb < 4; ++kb) qreg[qg][kb] = *(const bf16x8*)(Qb + kb * 32);
  }

  f32x4 ctx[2][8] = {};
  f32x4 lacc[2] = {};                      // unnormalized row-sums, ctx layout (q=4g+r)
  float m_[2] = {-1e30f, -1e30f};

  const short ONEB = (short)0x3F80;        // bf16 1.0
  const bf16x8 ones = {ONEB, ONEB, ONEB, ONEB, ONEB, ONEB, ONEB, ONEB};

  const int kvbeg = sp * (KVL_ / NS);
  const char* Kg = (const char*)(Km + (size_t)b * KVL_ * NCH) + h * 256;
  const char* Vg = (const char*)(Vt + (size_t)(b * H_ + h) * DH * KVL_);

  auto stage = [&](int bi, int kv0){       // 8 gload16/thread (256 threads)
    #pragma unroll
    for (int i = 0; i < 4; ++i){
      int lin = (i * 256 + tid) * 16;
      int sw  = lin ^ (((lin >> 8) & 7) << 4);
      gload16((char*)&Kbuf[bi][0][0] + lin,
              Kg + (size_t)(kv0 + (sw >> 8)) * 2048 + (sw & 255));
    }
    #pragma unroll
    for (int i = 0; i < 4; ++i){
      int lin = (i * 256 + tid) * 16;
      int sw  = lin ^ (((lin >> 7) & 7) << 4);
      gload16((char*)&Vbuf[bi][0][0] + lin,
              Vg + (size_t)(sw >> 7) * (KVL_ * 2) + kv0 * 2 + (sw & 127));
    }
  };

  const float THR = 11.5415603f;            // 8 * log2(e)
  const int NCHUNK = (KVL_ / NS) / KVBLK;   // 16

  stage(0, kvbeg);
  __syncthreads();

  for (int c = 0; c < NCHUNK; ++c){
    int bi = c & 1;
    if (c + 1 < NCHUNK) stage(bi ^ 1, kvbeg + (c + 1) * KVBLK);

    const char* Kl = (const char*)&Kbuf[bi][0][0];
    const char* Vl = (const char*)&Vbuf[bi][0][0];

    // QK^T swapped, K-frag loaded once and shared by both q-groups
    f32x4 s[2][4] = {};
    __builtin_amdgcn_s_setprio(1);
    #pragma unroll
    for (int kf = 0; kf < 4; ++kf){
      #pragma unroll
      for (int kb = 0; kb < 4; ++kb){
        int off = (kf * 16 + j) * 256 + kb * 64 + g * 16;
        off ^= ((j & 7) << 4);
        bf16x8 kfrag = *(const bf16x8*)(Kl + off);
        s[0][kf] = __builtin_amdgcn_mfma_f32_16x16x32_bf16(kfrag, qreg[0][kb], s[0][kf], 0, 0, 0);
        s[1][kf] = __builtin_amdgcn_mfma_f32_16x16x32_bf16(kfrag, qreg[1][kb], s[1][kf], 0, 0, 0);
      }
    }
    __builtin_amdgcn_s_setprio(0);

    union { unsigned u[4]; bf16x8 v; } pa[2][2];
    #pragma unroll
    for (int qg = 0; qg < 2; ++qg){
      float t0 = fmaxf(fmaxf(s[qg][0][0], s[qg][0][1]), fmaxf(s[qg][0][2], s[qg][0][3]));
      float t1 = fmaxf(fmaxf(s[qg][1][0], s[qg][1][1]), fmaxf(s[qg][1][2], s[qg][1][3]));
      float t2 = fmaxf(fmaxf(s[qg][2][0], s[qg][2][1]), fmaxf(s[qg][2][2], s[qg][2][3]));
      float t3 = fmaxf(fmaxf(s[qg][3][0], s[qg][3][1]), fmaxf(s[qg][3][2], s[qg][3][3]));
      float pm = fmaxf(fmaxf(t0, t1), fmaxf(t2, t3));
      pm = fmaxf(pm, __shfl_xor(pm, 16));
      pm = fmaxf(pm, __shfl_xor(pm, 32));
      int ok = (pm - m_[qg] <= THR);
      if (!__all(ok)){
        float mn = fmaxf(m_[qg], pm);
        float cf = exp2f(m_[qg] - mn);
        m_[qg] = mn;
        float cfr[4];
        #pragma unroll
        for (int r = 0; r < 4; ++r) cfr[r] = __shfl(cf, g * 4 + r);
        #pragma unroll
        for (int df = 0; df < 8; ++df)
          #pragma unroll
          for (int r = 0; r < 4; ++r) ctx[qg][df][r] *= cfr[r];
        #pragma unroll
        for (int r = 0; r < 4; ++r) lacc[qg][r] *= cfr[r];
      }
      #pragma unroll
      for (int kf = 0; kf < 4; ++kf)
        #pragma unroll
        for (int r = 0; r < 4; ++r)
          s[qg][kf][r] = exp2f(s[qg][kf][r] - m_[qg]);
      #pragma unroll
      for (int kb = 0; kb < 2; ++kb){
        asm("v_cvt_pk_bf16_f32 %0, %1, %2" : "=v"(pa[qg][kb].u[0]) : "v"(s[qg][2*kb][0]),   "v"(s[qg][2*kb][1]));
        asm("v_cvt_pk_bf16_f32 %0, %1, %2" : "=v"(pa[qg][kb].u[1]) : "v"(s[qg][2*kb][2]),   "v"(s[qg][2*kb][3]));
        asm("v_cvt_pk_bf16_f32 %0, %1, %2" : "=v"(pa[qg][kb].u[2]) : "v"(s[qg][2*kb+1][0]), "v"(s[qg][2*kb+1][1]));
        asm("v_cvt_pk_bf16_f32 %0, %1, %2" : "=v"(pa[qg][kb].u[3]) : "v"(s[qg][2*kb+1][2]), "v"(s[qg][2*kb+1][3]));
      }
    }

    // PV + l-sum: V-frag loaded once, shared by both q-groups; ones-MFMA row-sums P
    __builtin_amdgcn_s_setprio(1);
    lacc[0] = __builtin_amdgcn_mfma_f32_16x16x32_bf16(pa[0][0].v, ones, lacc[0], 0, 0, 0);
    lacc[0] = __builtin_amdgcn_mfma_f32_16x16x32_bf16(pa[0][1].v, ones, lacc[0], 0, 0, 0);
    lacc[1] = __builtin_amdgcn_mfma_f32_16x16x32_bf16(pa[1][0].v, ones, lacc[1], 0, 0, 0);
    lacc[1] = __builtin_amdgcn_mfma_f32_16x16x32_bf16(pa[1][1].v, ones, lacc[1], 0, 0, 0);
    #pragma unroll
    for (int df = 0; df < 8; ++df){
      int off0 = (df * 16 + j) * 128 + g * 16;        int o0 = off0 ^ ((j & 7) << 4);
      int off1 = (df * 16 + j) * 128 + 64 + g * 16;   int o1 = off1 ^ ((j & 7) << 4);
      bf16x8 v0 = *(const bf16x8*)(Vl + o0);
      bf16x8 v1 = *(const bf16x8*)(Vl + o1);
      ctx[0][df] = __builtin_amdgcn_mfma_f32_16x16x32_bf16(pa[0][0].v, v0, ctx[0][df], 0, 0, 0);
      ctx[0][df] = __builtin_amdgcn_mfma_f32_16x16x32_bf16(pa[0][1].v, v1, ctx[0][df], 0, 0, 0);
      ctx[1][df] = __builtin_amdgcn_mfma_f32_16x16x32_bf16(pa[1][0].v, v0, ctx[1][df], 0, 0, 0);
      ctx[1][df] = __builtin_amdgcn_mfma_f32_16x16x32_bf16(pa[1][1].v, v1, ctx[1][df], 0, 0, 0);
    }
    __builtin_amdgcn_s_setprio(0);
    __syncthreads();
  }

  #pragma unroll
  for (int qg = 0; qg < 2; ++qg){
    size_t prow0 = ((size_t)sp * 32 + bh) * QL_ + qbase + qg * 16;
    #pragma unroll
    for (int r = 0; r < 4; ++r){
      ushort_t* cp = ctxp + (prow0 + g * 4 + r) * DH;
      #pragma unroll
      for (int df = 0; df < 8; ++df) cp[df * 16 + j] = f2bf(ctx[qg][df][r]);
    }
    if (j == 0){
      #pragma unroll
      for (int r = 0; r < 4; ++r)
        mlp[(prow0 + g * 4 + r) * 2 + 1] = lacc[qg][r];
    }
    if (g == 0)
      mlp[(prow0 + j) * 2] = m_[qg];
  }
}

// ---------------- Split combine: 1 wave per q-row (m in log2 domain, bf16 ctx) ----------------
__global__ __launch_bounds__(256)
void combine_kernel(const ushort_t* __restrict__ ctxp, const float* __restrict__ mlp,
                    float* __restrict__ out){
  int row = blockIdx.x * 4 + (threadIdx.x >> 6);   // (b*8+h)*512 + q
  int lane = threadIdx.x & 63;
  int b = row >> 12, h = (row >> 9) & 7, q = row & 511;
  float ms[NS], ls[NS];
  #pragma unroll
  for (int s = 0; s < NS; ++s){
    ms[s] = mlp[((size_t)(s * NROWS + row)) * 2];
    ls[s] = mlp[((size_t)(s * NROWS + row)) * 2 + 1];
  }
  float M = ms[0];
  #pragma unroll
  for (int s = 1; s < NS; ++s) M = fmaxf(M, ms[s]);
  float wgt[NS], L = 0.f;
  #pragma unroll
  for (int s = 0; s < NS; ++s){ wgt[s] = exp2f(ms[s] - M); L += ls[s] * wgt[s]; }
  float inv = 1.f / L;
  float ax = 0.f, ay = 0.f;
  #pragma unroll
  for (int s = 0; s < NS; ++s){
    unsigned pk = *(const unsigned*)(ctxp + ((size_t)(s * NROWS + row)) * DH + lane * 2);
    ax += bf2f(pk & 0xFFFFu) * wgt[s];
    ay += bf2f(pk >> 16) * wgt[s];
  }
  float* op = out + ((size_t)(b * QL_ + q)) * NCH + h * DH + lane * 2;
  op[0] = ax * inv; op[1] = ay * inv;
}

extern "C" void kernel_launch(void* const* d_in, const int* in_sizes, int n_in,
                              void* d_out, int out_size, void* d_ws, size_t ws_size,
                              hipStream_t stream){
  const float* hs   = (const float*)d_in[0];
  const float* inp  = (const float*)d_in[1];
  const float* ln1g = (const float*)d_in[2];
  const float* ln1b = (const float*)d_in[3];
  const float* ln2g = (const float*)d_in[4];
  const float* ln2b = (const float*)d_in[5];
  const float* Wq   = (const float*)d_in[6];
  const float* bq   = (const float*)d_in[7];
  const float* Wk   = (const float*)d_in[8];
  const float* bk   = (const float*)d_in[9];
  const float* Wv   = (const float*)d_in[10];
  const float* bv   = (const float*)d_in[11];

  char* ws = (char*)d_ws;
  size_t off = 0;
  auto alloc = [&](size_t bytes){ void* pp = ws + off; off += (bytes + 255) & ~255ull; return pp; };
  // persistent across phases
  ushort_t* Qm = (ushort_t*)alloc((size_t)2048 * 1024 * 2);
  ushort_t* Km = (ushort_t*)alloc((size_t)16384 * 1024 * 2);
  ushort_t* Vt = (ushort_t*)alloc((size_t)16384 * 1024 * 2);
  size_t base2 = off;
  // phase 1: LN outputs + transposed weights (dead after the GEMMs)
  ushort_t* hs_ln = (ushort_t*)alloc((size_t)2048 * 1024 * 2);
  ushort_t* in_ln = (ushort_t*)alloc((size_t)16384 * 768 * 2);
  ushort_t* Wqt   = (ushort_t*)alloc((size_t)1024 * 1024 * 2);
  ushort_t* Wkt   = (ushort_t*)alloc((size_t)1024 * 768 * 2);
  ushort_t* Wvt   = (ushort_t*)alloc((size_t)1024 * 768 * 2);
  // phase 2: attention partials (alias phase 1)
  off = base2;
  ushort_t* ctxp = (ushort_t*)alloc((size_t)NS * NROWS * DH * 2);
  float*    mlp  = (float*)alloc((size_t)NS * NROWS * 2 * 4);

  const float QSC = 0.08838834764831845f * 1.4426950408889634f;  // 1/sqrt(128)*log2(e)

  pre_kernel<<<7680, 256, 0, stream>>>(hs, ln1g, ln1b, hs_ln, inp, ln2g, ln2b, in_ln,
                                       Wq, Wqt, Wk, Wkt, Wv, Wvt);
  gemm_kernel<<<dim3(16, 8), 256, 0, stream>>>(hs_ln, Wqt, bq, Qm, 2048, 1024, QSC);
  gemm256_kernel<false><<<dim3(64, 4), 512, 0, stream>>>(in_ln, Wkt, bk, Km, 16384, 768, 1.0f);
  gemm256_kernel<true ><<<dim3(64, 4), 512, 0, stream>>>(in_ln, Wvt, bv, Vt, 16384, 768, 1.0f);
  attn_kernel<<<512, 256, 0, stream>>>(Qm, Km, Vt, ctxp, mlp);
  combine_kernel<<<NROWS / 4, 256, 0, stream>>>(ctxp, mlp, (float*)d_out);
}